// Round 11
// baseline (184.280 us; speedup 1.0000x reference)
//
#include <hip/hip_runtime.h>
#include <math.h>

typedef _Float16 f16;

constexpr int NN   = 100000;  // nodes
constexpr int DIN  = 128;
constexpr int DH   = 16;      // hidden
constexpr int NC   = 40;      // classes
constexpr int CAP  = 48;      // per-node neighbor capacity; P(Poisson(16) > 48) ~ 1e-11
constexpr int NB   = (NN + 127) / 128;   // 782 buckets of 128 dst nodes
constexpr int BC   = 2816;               // per-bucket edge capacity; mean 2048, +17 sigma
constexpr int BSTR = 16;                 // bcur stride: one counter per 64B line

static_assert(NN % 8 == 0, "agg grids assume NN % 8 == 0");

// ---------------- k_part: edges -> fixed-capacity bucket regions ----------------
// 1024 thr x 8 edges, int4 loads; LDS hist -> one global atomic per (block,bucket)
// (padded bcur: no line contention) -> scatter packed (src<<7)|(dst&127).
// Homogeneous blocks only (round-6/round-10 lesson: heterogeneous fusion stragglers
// cost more than the 4-5us launch they save).
template <bool VEC4>
__global__ __launch_bounds__(1024)
void k_part(const int* __restrict__ src, const int* __restrict__ dst, int E,
            int* __restrict__ bcur, int* __restrict__ part)
{
    __shared__ int lh[NB];
    __shared__ int lbase[NB];
    int t = threadIdx.x;                              // 1024
    for (int i = t; i < NB; i += 1024) lh[i] = 0;
    __syncthreads();
    long base = (long)blockIdx.x * 8192;
    int pk[8], bk[8], rk[8];
    if (VEC4 && base + 8192 <= (long)E) {
        const int4* s4 = (const int4*)(src + base) + t * 2;
        const int4* d4 = (const int4*)(dst + base) + t * 2;
        int4 sa = s4[0], sb = s4[1];
        int4 da = d4[0], db = d4[1];
        int ss[8] = {sa.x, sa.y, sa.z, sa.w, sb.x, sb.y, sb.z, sb.w};
        int dd[8] = {da.x, da.y, da.z, da.w, db.x, db.y, db.z, db.w};
        #pragma unroll
        for (int i = 0; i < 8; ++i) {
            bk[i] = dd[i] >> 7;
            pk[i] = (ss[i] << 7) | (dd[i] & 127);     // src < 2^17, fits
            rk[i] = atomicAdd(&lh[bk[i]], 1);
        }
    } else {
        #pragma unroll
        for (int i = 0; i < 8; ++i) {
            long e = base + (long)t * 8 + i;
            if (e < E) {
                int s = src[e], d = dst[e];
                bk[i] = d >> 7;
                pk[i] = (s << 7) | (d & 127);
                rk[i] = atomicAdd(&lh[bk[i]], 1);
            } else bk[i] = -1;
        }
    }
    __syncthreads();
    for (int i = t; i < NB; i += 1024)
        lbase[i] = lh[i] ? atomicAdd(&bcur[i * BSTR], lh[i]) : 0;
    __syncthreads();
    #pragma unroll
    for (int i = 0; i < 8; ++i) {
        if (bk[i] >= 0) {
            int idx = lbase[bk[i]] + rk[i];
            if (idx < BC) part[(long)bk[i] * BC + idx] = pk[i];
        }
    }
}

// ---------------- k_proj: 64 nodes/block, thread = (node, half, k-half) ----------------
// half & k-half wave-uniform (readfirstlane) -> weight reads stay scalar; x read directly
// (16 independent float4 loads/thread); one LDS combine of the two k-partials.
// p1l stored fp16 (3.2MB gather table, L2-resident), p1r f32. 1563 uniform 256-thr blocks.
__global__ void k_proj(const float* __restrict__ x,
                       const float* __restrict__ W1l, const float* __restrict__ W1r,
                       f16* __restrict__ p1h, float* __restrict__ p1r)
{
    __shared__ float ps[2][64][DH + 1];            // partial sums from kh=1 waves
    int t  = threadIdx.x;
    int nl = t & 63;
    int halfu = __builtin_amdgcn_readfirstlane((t >> 6) & 1);   // wave-uniform
    int khu   = __builtin_amdgcn_readfirstlane(t >> 7);         // wave-uniform
    long n  = (long)blockIdx.x * 64 + nl;
    long ncl = n < NN ? n : NN - 1;                // clamp loads, guard stores
    const float4* xr = (const float4*)(x + ncl * DIN + khu * 64);
    const float*  Wk = (halfu ? W1r : W1l) + khu * 64 * DH;

    float acc[DH];
    #pragma unroll
    for (int j = 0; j < DH; ++j) acc[j] = 0.f;
    #pragma unroll
    for (int k4 = 0; k4 < 16; ++k4) {
        float4 v = xr[k4];
        const float* wr = Wk + k4 * 4 * DH;        // wave-uniform -> s_load
        #pragma unroll
        for (int j = 0; j < DH; ++j) {
            acc[j] = fmaf(v.x, wr[j],          acc[j]);
            acc[j] = fmaf(v.y, wr[DH + j],     acc[j]);
            acc[j] = fmaf(v.z, wr[2 * DH + j], acc[j]);
            acc[j] = fmaf(v.w, wr[3 * DH + j], acc[j]);
        }
    }
    if (khu) {
        #pragma unroll
        for (int j = 0; j < DH; ++j) ps[halfu][nl][j] = acc[j];
    }
    __syncthreads();
    if (!khu && n < NN) {
        #pragma unroll
        for (int j = 0; j < DH; ++j) acc[j] += ps[halfu][nl][j];
        if (halfu == 0) {
            union { f16 f[16]; uint4 q[2]; } u;
            #pragma unroll
            for (int j = 0; j < DH; ++j) u.f[j] = (f16)acc[j];
            uint4* po = (uint4*)(p1h + n * DH);
            po[0] = u.q[0]; po[1] = u.q[1];
        } else {
            float4* pr = (float4*)(p1r + n * DH);
            pr[0] = make_float4(acc[0],  acc[1],  acc[2],  acc[3]);
            pr[1] = make_float4(acc[4],  acc[5],  acc[6],  acc[7]);
            pr[2] = make_float4(acc[8],  acc[9],  acc[10], acc[11]);
            pr[3] = make_float4(acc[12], acc[13], acc[14], acc[15]);
        }
    }
}

// ---------------- k_ba1: fused col-build (LDS) + layer-1 aggregate ----------------
// One block per 128-node bucket, 512 threads. Phase A: build col in LDS via low-
// contention LDS int atomics. Export cnt + col (coalesced) for agg2o. Phase B: 4
// lanes/node (2 dim-halves x 2 neighbor-groups) uint4 gathers, indices from LDS.
__global__ __launch_bounds__(512)
void k_ba1(const int* __restrict__ bcur, const int* __restrict__ part,
           const uint4* __restrict__ g4, const float4* __restrict__ p1r4,
           const float* __restrict__ b1,
           int* __restrict__ cnt, int* __restrict__ col, uint4* __restrict__ h4)
{
    __shared__ int scol[128 * CAP];          // 24.6 KB
    __shared__ int cur[128];
    int t = threadIdx.x, b = blockIdx.x;
    if (t < 128) cur[t] = 0;
    __syncthreads();
    long base = (long)b * BC;
    int ne = min(bcur[b * BSTR], BC);
    for (int e = t; e < ne; e += 512) {
        int pk = part[base + e];
        int dl = pk & 127;
        int r  = atomicAdd(&cur[dl], 1);     // ~16 hits/counter: low contention
        if (r < CAP) scol[dl * CAP + r] = pk >> 7;
    }
    __syncthreads();
    if (t < 128) {
        int node = (b << 7) + t;
        if (node < NN) cnt[node] = cur[t];
    }
    int* gcol = col + (long)b * 128 * CAP;
    for (int i = t; i < 128 * CAP; i += 512) gcol[i] = scol[i];

    // ---- phase B: aggregate from LDS col ----
    int nl = t >> 2, dh = (t >> 1) & 1, ng = t & 1;
    int node = (b << 7) + nl;
    int degf = cur[nl];
    int deg  = min(degf, CAP);
    const int* cb = scol + nl * CAP;
    float a[8];
    #pragma unroll
    for (int j = 0; j < 8; ++j) a[j] = 0.f;
    int i = ng;
    for (; i + 6 < deg; i += 8) {
        int s0 = cb[i], s1 = cb[i+2], s2 = cb[i+4], s3 = cb[i+6];
        uint4 v0 = g4[(long)s0*2+dh], v1 = g4[(long)s1*2+dh],
              v2 = g4[(long)s2*2+dh], v3 = g4[(long)s3*2+dh];
        const f16 *p0=(const f16*)&v0, *p1=(const f16*)&v1,
                  *p2=(const f16*)&v2, *p3=(const f16*)&v3;
        #pragma unroll
        for (int j = 0; j < 8; ++j)
            a[j] += (float)p0[j] + (float)p1[j] + (float)p2[j] + (float)p3[j];
    }
    for (; i < deg; i += 2) {
        int s = cb[i];
        uint4 v = g4[(long)s*2+dh];
        const f16* p = (const f16*)&v;
        #pragma unroll
        for (int j = 0; j < 8; ++j) a[j] += (float)p[j];
    }
    #pragma unroll
    for (int j = 0; j < 8; ++j) a[j] += __shfl_xor(a[j], 1);
    if (ng == 0 && node < NN) {
        float inv = 1.0f / fmaxf((float)degf, 1.0f);
        float4 bl = ((const float4*)b1)[dh*2+0];
        float4 bh = ((const float4*)b1)[dh*2+1];
        float4 rl = p1r4[(long)node*4 + dh*2+0];
        float4 rh = p1r4[(long)node*4 + dh*2+1];
        float bb[8] = {bl.x,bl.y,bl.z,bl.w, bh.x,bh.y,bh.z,bh.w};
        float rr[8] = {rl.x,rl.y,rl.z,rl.w, rh.x,rh.y,rh.z,rh.w};
        union { f16 f[8]; uint4 u; } o;
        #pragma unroll
        for (int j = 0; j < 8; ++j)
            o.f[j] = (f16)fmaxf(fmaf(a[j], inv, bb[j] + rr[j]), 0.f);
        h4[(long)node*2+dh] = o.u;
    }
}

// ---------------- k_agg2o: layer-2 aggregate + proj2 + log_softmax (unchanged) ---------
__global__ void k_agg2o(const int* __restrict__ cnt, const int* __restrict__ col,
                        const uint4* __restrict__ g4,
                        const float* __restrict__ W2l, const float* __restrict__ b2,
                        const float* __restrict__ W2r, float* __restrict__ out)
{
    __shared__ float sW[2 * DH * NC + NC];   // W2l | W2r | b2
    __shared__ float sA[32][DH + 1];         // per-node mean agg
    __shared__ float sH[32][DH + 1];         // per-node root h
    int t = threadIdx.x;                     // 256
    for (int i = t; i < DH * NC; i += 256) {
        sW[i]           = W2l[i];
        sW[DH * NC + i] = W2r[i];
    }
    if (t < NC) sW[2 * DH * NC + t] = b2[t];

    int lane = t & 63;
    int wv   = (blockIdx.x * 256 + t) >> 6;
    int n    = wv * 8 + (lane >> 3);         // grid exact: always < NN
    int dh   = (lane >> 2) & 1;
    int ng   = lane & 3;
    int nl2  = t >> 3;                       // node-local 0..31
    int degf = cnt[n];
    int deg  = min(degf, CAP);
    const int* cb = col + (long)n * CAP;
    float a[8];
    #pragma unroll
    for (int j = 0; j < 8; ++j) a[j] = 0.f;
    int i = ng;
    for (; i + 12 < deg; i += 16) {
        int s0 = cb[i], s1 = cb[i+4], s2 = cb[i+8], s3 = cb[i+12];
        uint4 v0 = g4[(long)s0*2+dh], v1 = g4[(long)s1*2+dh],
              v2 = g4[(long)s2*2+dh], v3 = g4[(long)s3*2+dh];
        const f16 *p0=(const f16*)&v0, *p1=(const f16*)&v1,
                  *p2=(const f16*)&v2, *p3=(const f16*)&v3;
        #pragma unroll
        for (int j = 0; j < 8; ++j)
            a[j] += (float)p0[j] + (float)p1[j] + (float)p2[j] + (float)p3[j];
    }
    for (; i < deg; i += 4) {
        int s = cb[i];
        uint4 v = g4[(long)s*2+dh];
        const f16* p = (const f16*)&v;
        #pragma unroll
        for (int j = 0; j < 8; ++j) a[j] += (float)p[j];
    }
    #pragma unroll
    for (int j = 0; j < 8; ++j) {
        a[j] += __shfl_xor(a[j], 1);
        a[j] += __shfl_xor(a[j], 2);
    }
    if (ng == 0) {
        float inv = 1.0f / fmaxf((float)degf, 1.0f);
        #pragma unroll
        for (int j = 0; j < 8; ++j) sA[nl2][dh*8+j] = a[j] * inv;
    } else if (ng == 1) {
        uint4 hv4 = g4[(long)n*2+dh];        // root h row half
        const f16* hp = (const f16*)&hv4;
        #pragma unroll
        for (int j = 0; j < 8; ++j) sH[nl2][dh*8+j] = (float)hp[j];
    }
    __syncthreads();

    float av[DH], hv[DH];
    #pragma unroll
    for (int j = 0; j < DH; ++j) { av[j] = sA[nl2][j]; hv[j] = sH[nl2][j]; }
    int lane8 = t & 7;                       // class stride lane: c = lane8 + 8*j
    float o[5];
    #pragma unroll
    for (int j = 0; j < 5; ++j) {
        int c = lane8 + 8 * j;
        float acc = sW[2 * DH * NC + c];
        #pragma unroll
        for (int k = 0; k < DH; ++k) {
            acc = fmaf(av[k], sW[k * NC + c],           acc);
            acc = fmaf(hv[k], sW[DH * NC + k * NC + c], acc);
        }
        o[j] = acc;
    }
    float mx = o[0];
    #pragma unroll
    for (int j = 1; j < 5; ++j) mx = fmaxf(mx, o[j]);
    #pragma unroll
    for (int m = 1; m <= 4; m <<= 1) mx = fmaxf(mx, __shfl_xor(mx, m));
    float s = 0.f;
    #pragma unroll
    for (int j = 0; j < 5; ++j) s += __expf(o[j] - mx);
    #pragma unroll
    for (int m = 1; m <= 4; m <<= 1) s += __shfl_xor(s, m);
    float lg = mx + __logf(s);
    float* op = out + (long)n * NC;
    #pragma unroll
    for (int j = 0; j < 5; ++j) op[lane8 + 8 * j] = o[j] - lg;   // coalesced across lanes
}

// ---------------- launch ----------------

extern "C" void kernel_launch(void* const* d_in, const int* in_sizes, int n_in,
                              void* d_out, int out_size, void* d_ws, size_t ws_size,
                              hipStream_t stream) {
    const float* x   = (const float*)d_in[0];
    const int*   ei  = (const int*)d_in[1];   // [2, E] int32
    const float* W1l = (const float*)d_in[2];
    const float* b1  = (const float*)d_in[3];
    const float* W1r = (const float*)d_in[4];
    const float* W2l = (const float*)d_in[5];
    const float* b2  = (const float*)d_in[6];
    const float* W2r = (const float*)d_in[7];
    float* out = (float*)d_out;

    const int E = in_sizes[1] / 2;
    const int* src = ei;
    const int* dst = ei + E;

    // ws (4B units): bcur[NB*16 pad 12544] | cnt[NN] | col[NB*128*CAP] | part[NB*BC] |
    //                p1r[16N f32] | p1h[16N f16] | h[16N f16]   (~41 MB)
    int* bcur = (int*)d_ws;
    int* cnt  = bcur + 12544;
    int* col  = cnt + NN;
    int* part = col + (long)NB * 128 * CAP;
    float* p1r = (float*)(part + (long)NB * BC);
    f16*   p1h = (f16*)(p1r + (long)NN * DH);
    f16*   h   = p1h + (long)NN * DH;

    hipMemsetAsync(bcur, 0, NB * BSTR * sizeof(int), stream);

    if ((E & 3) == 0)
        k_part<true ><<<(E + 8191) / 8192, 1024, 0, stream>>>(src, dst, E, bcur, part);
    else
        k_part<false><<<(E + 8191) / 8192, 1024, 0, stream>>>(src, dst, E, bcur, part);

    k_proj <<<(NN + 63) / 64, 256, 0, stream>>>(x, W1l, W1r, p1h, p1r);

    k_ba1  <<<NB, 512, 0, stream>>>(bcur, part, (const uint4*)p1h,
                                    (const float4*)p1r, b1, cnt, col, (uint4*)h);
    k_agg2o<<<(NN + 31) / 32, 256, 0, stream>>>(cnt, col, (const uint4*)h,
                                                W2l, b2, W2r, out);
}

// Round 13
// 179.261 us; speedup vs baseline: 1.0280x; 1.0280x over previous
//
#include <hip/hip_runtime.h>
#include <math.h>

typedef _Float16 f16;

constexpr int NN   = 100000;  // nodes
constexpr int DIN  = 128;
constexpr int DH   = 16;      // hidden
constexpr int NC   = 40;      // classes
constexpr int CAP  = 48;      // per-node neighbor capacity; P(Poisson(16) > 48) ~ 1e-11
constexpr int NB   = (NN + 127) / 128;   // 782 buckets of 128 dst nodes
constexpr int BC   = 2816;               // per-bucket edge capacity; mean 2048, +17 sigma
constexpr int BSTR = 16;                 // bcur stride: one counter per 64B line

static_assert(NN % 8 == 0, "grids assume NN % 8 == 0");

// ---------------- k_part: edges -> fixed-capacity bucket regions (proven R10) ----------
template <bool VEC4>
__global__ __launch_bounds__(1024)
void k_part(const int* __restrict__ src, const int* __restrict__ dst, int E,
            int* __restrict__ bcur, int* __restrict__ part)
{
    __shared__ int lh[NB];
    __shared__ int lbase[NB];
    int t = threadIdx.x;                              // 1024
    for (int i = t; i < NB; i += 1024) lh[i] = 0;
    __syncthreads();
    long base = (long)blockIdx.x * 8192;
    int pk[8], bk[8], rk[8];
    if (VEC4 && base + 8192 <= (long)E) {
        const int4* s4 = (const int4*)(src + base) + t * 2;
        const int4* d4 = (const int4*)(dst + base) + t * 2;
        int4 sa = s4[0], sb = s4[1];
        int4 da = d4[0], db = d4[1];
        int ss[8] = {sa.x, sa.y, sa.z, sa.w, sb.x, sb.y, sb.z, sb.w};
        int dd[8] = {da.x, da.y, da.z, da.w, db.x, db.y, db.z, db.w};
        #pragma unroll
        for (int i = 0; i < 8; ++i) {
            bk[i] = dd[i] >> 7;
            pk[i] = (ss[i] << 7) | (dd[i] & 127);     // src < 2^17, fits
            rk[i] = atomicAdd(&lh[bk[i]], 1);
        }
    } else {
        #pragma unroll
        for (int i = 0; i < 8; ++i) {
            long e = base + (long)t * 8 + i;
            if (e < E) {
                int s = src[e], d = dst[e];
                bk[i] = d >> 7;
                pk[i] = (s << 7) | (d & 127);
                rk[i] = atomicAdd(&lh[bk[i]], 1);
            } else bk[i] = -1;
        }
    }
    __syncthreads();
    for (int i = t; i < NB; i += 1024)
        lbase[i] = lh[i] ? atomicAdd(&bcur[i * BSTR], lh[i]) : 0;
    __syncthreads();
    #pragma unroll
    for (int i = 0; i < 8; ++i) {
        if (bk[i] >= 0) {
            int idx = lbase[bk[i]] + rk[i];
            if (idx < BC) part[(long)bk[i] * BC + idx] = pk[i];
        }
    }
}

// ---------------- k_proj: 64 nodes/block, thread = (node, half, k-half) (proven) -------
__global__ void k_proj(const float* __restrict__ x,
                       const float* __restrict__ W1l, const float* __restrict__ W1r,
                       f16* __restrict__ p1h, float* __restrict__ p1r)
{
    __shared__ float ps[2][64][DH + 1];            // partial sums from kh=1 waves
    int t  = threadIdx.x;
    int nl = t & 63;
    int halfu = __builtin_amdgcn_readfirstlane((t >> 6) & 1);   // wave-uniform
    int khu   = __builtin_amdgcn_readfirstlane(t >> 7);         // wave-uniform
    long n  = (long)blockIdx.x * 64 + nl;
    long ncl = n < NN ? n : NN - 1;                // clamp loads, guard stores
    const float4* xr = (const float4*)(x + ncl * DIN + khu * 64);
    const float*  Wk = (halfu ? W1r : W1l) + khu * 64 * DH;

    float acc[DH];
    #pragma unroll
    for (int j = 0; j < DH; ++j) acc[j] = 0.f;
    #pragma unroll
    for (int k4 = 0; k4 < 16; ++k4) {
        float4 v = xr[k4];
        const float* wr = Wk + k4 * 4 * DH;        // wave-uniform -> s_load
        #pragma unroll
        for (int j = 0; j < DH; ++j) {
            acc[j] = fmaf(v.x, wr[j],          acc[j]);
            acc[j] = fmaf(v.y, wr[DH + j],     acc[j]);
            acc[j] = fmaf(v.z, wr[2 * DH + j], acc[j]);
            acc[j] = fmaf(v.w, wr[3 * DH + j], acc[j]);
        }
    }
    if (khu) {
        #pragma unroll
        for (int j = 0; j < DH; ++j) ps[halfu][nl][j] = acc[j];
    }
    __syncthreads();
    if (!khu && n < NN) {
        #pragma unroll
        for (int j = 0; j < DH; ++j) acc[j] += ps[halfu][nl][j];
        if (halfu == 0) {
            union { f16 f[16]; uint4 q[2]; } u;
            #pragma unroll
            for (int j = 0; j < DH; ++j) u.f[j] = (f16)acc[j];
            uint4* po = (uint4*)(p1h + n * DH);
            po[0] = u.q[0]; po[1] = u.q[1];
        } else {
            float4* pr = (float4*)(p1r + n * DH);
            pr[0] = make_float4(acc[0],  acc[1],  acc[2],  acc[3]);
            pr[1] = make_float4(acc[4],  acc[5],  acc[6],  acc[7]);
            pr[2] = make_float4(acc[8],  acc[9],  acc[10], acc[11]);
            pr[3] = make_float4(acc[12], acc[13], acc[14], acc[15]);
        }
    }
}

// ---------------- k_ba1: col-build (LDS) + layer-1 aggregate; NO col export ------------
// One block per 128-node bucket, 512 threads. Phase A: scol via low-contention LDS int
// atomics. Phase B: 4 lanes/node (2 dim-halves x 2 neighbor-groups) uint4 gathers,
// indices from LDS. h written fp16. (k_ba2 rebuilds scol itself -> no export needed.)
__global__ __launch_bounds__(512)
void k_ba1(const int* __restrict__ bcur, const int* __restrict__ part,
           const uint4* __restrict__ g4, const float4* __restrict__ p1r4,
           const float* __restrict__ b1, uint4* __restrict__ h4)
{
    __shared__ int scol[128 * CAP];          // 24.6 KB
    __shared__ int cur[128];
    int t = threadIdx.x, b = blockIdx.x;
    if (t < 128) cur[t] = 0;
    __syncthreads();
    long base = (long)b * BC;
    int ne = min(bcur[b * BSTR], BC);
    for (int e = t; e < ne; e += 512) {
        int pk = part[base + e];
        int dl = pk & 127;
        int r  = atomicAdd(&cur[dl], 1);     // ~16 hits/counter: low contention
        if (r < CAP) scol[dl * CAP + r] = pk >> 7;
    }
    __syncthreads();

    int nl = t >> 2, dh = (t >> 1) & 1, ng = t & 1;
    int node = (b << 7) + nl;
    int degf = cur[nl];
    int deg  = min(degf, CAP);
    const int* cb = scol + nl * CAP;
    float a[8];
    #pragma unroll
    for (int j = 0; j < 8; ++j) a[j] = 0.f;
    int i = ng;
    for (; i + 6 < deg; i += 8) {
        int s0 = cb[i], s1 = cb[i+2], s2 = cb[i+4], s3 = cb[i+6];
        uint4 v0 = g4[(long)s0*2+dh], v1 = g4[(long)s1*2+dh],
              v2 = g4[(long)s2*2+dh], v3 = g4[(long)s3*2+dh];
        const f16 *p0=(const f16*)&v0, *p1=(const f16*)&v1,
                  *p2=(const f16*)&v2, *p3=(const f16*)&v3;
        #pragma unroll
        for (int j = 0; j < 8; ++j)
            a[j] += (float)p0[j] + (float)p1[j] + (float)p2[j] + (float)p3[j];
    }
    for (; i < deg; i += 2) {
        int s = cb[i];
        uint4 v = g4[(long)s*2+dh];
        const f16* p = (const f16*)&v;
        #pragma unroll
        for (int j = 0; j < 8; ++j) a[j] += (float)p[j];
    }
    #pragma unroll
    for (int j = 0; j < 8; ++j) a[j] += __shfl_xor(a[j], 1);
    if (ng == 0 && node < NN) {
        float inv = 1.0f / fmaxf((float)degf, 1.0f);
        float4 bl = ((const float4*)b1)[dh*2+0];
        float4 bh = ((const float4*)b1)[dh*2+1];
        float4 rl = p1r4[(long)node*4 + dh*2+0];
        float4 rh = p1r4[(long)node*4 + dh*2+1];
        float bb[8] = {bl.x,bl.y,bl.z,bl.w, bh.x,bh.y,bh.z,bh.w};
        float rr[8] = {rl.x,rl.y,rl.z,rl.w, rh.x,rh.y,rh.z,rh.w};
        union { f16 f[8]; uint4 u; } o;
        #pragma unroll
        for (int j = 0; j < 8; ++j)
            o.f[j] = (f16)fmaxf(fmaf(a[j], inv, bb[j] + rr[j]), 0.f);
        h4[(long)node*2+dh] = o.u;
    }
}

// ---------------- k_ba2: scol rebuild + layer-2 aggregate + proj2 + log_softmax --------
// Same bucket geometry. Phase A: rebuild scol from part (coalesced re-read; proven-cheap
// pattern). Phase B: layer-2 gather on h with indices from LDS. Then overlay scol's LDS
// with sA|sH|sW (22.7KB <= 24.6KB) for the class matmul + softmax tail.
__global__ __launch_bounds__(512)
void k_ba2(const int* __restrict__ bcur, const int* __restrict__ part,
           const uint4* __restrict__ h4,
           const float* __restrict__ W2l, const float* __restrict__ b2,
           const float* __restrict__ W2r, float* __restrict__ out)
{
    __shared__ int scol[128 * CAP];          // 24.6 KB; overlaid by sA|sH|sW in the tail
    __shared__ int cur[128];
    int t = threadIdx.x, b = blockIdx.x;
    if (t < 128) cur[t] = 0;
    __syncthreads();
    long base = (long)b * BC;
    int ne = min(bcur[b * BSTR], BC);
    for (int e = t; e < ne; e += 512) {
        int pk = part[base + e];
        int dl = pk & 127;
        int r  = atomicAdd(&cur[dl], 1);
        if (r < CAP) scol[dl * CAP + r] = pk >> 7;
    }
    __syncthreads();

    int nl = t >> 2, dh = (t >> 1) & 1, ng = t & 1;
    int node = (b << 7) + nl;
    int degf = cur[nl];
    int deg  = min(degf, CAP);
    const int* cb = scol + nl * CAP;
    float a[8];
    #pragma unroll
    for (int j = 0; j < 8; ++j) a[j] = 0.f;
    int i = ng;
    for (; i + 6 < deg; i += 8) {
        int s0 = cb[i], s1 = cb[i+2], s2 = cb[i+4], s3 = cb[i+6];
        uint4 v0 = h4[(long)s0*2+dh], v1 = h4[(long)s1*2+dh],
              v2 = h4[(long)s2*2+dh], v3 = h4[(long)s3*2+dh];
        const f16 *p0=(const f16*)&v0, *p1=(const f16*)&v1,
                  *p2=(const f16*)&v2, *p3=(const f16*)&v3;
        #pragma unroll
        for (int j = 0; j < 8; ++j)
            a[j] += (float)p0[j] + (float)p1[j] + (float)p2[j] + (float)p3[j];
    }
    for (; i < deg; i += 2) {
        int s = cb[i];
        uint4 v = h4[(long)s*2+dh];
        const f16* p = (const f16*)&v;
        #pragma unroll
        for (int j = 0; j < 8; ++j) a[j] += (float)p[j];
    }
    #pragma unroll
    for (int j = 0; j < 8; ++j) a[j] += __shfl_xor(a[j], 1);
    long nodec = node < NN ? (long)node : 0;
    uint4 rv = h4[nodec*2+dh];               // root h half (any lane may read)
    __syncthreads();                         // all scol reads done -> overlay safe

    float* sA = (float*)scol;                // [128][17]
    float* sH = sA + 128 * 17;               // [128][17]
    float* sW = sH + 128 * 17;               // W2l | W2r | b2 (1320 floats; tot 22.7KB)
    if (ng == 0) {
        float inv = 1.0f / fmaxf((float)degf, 1.0f);
        #pragma unroll
        for (int j = 0; j < 8; ++j) sA[nl*17 + dh*8 + j] = a[j] * inv;
    } else {
        const f16* rp = (const f16*)&rv;
        #pragma unroll
        for (int j = 0; j < 8; ++j) sH[nl*17 + dh*8 + j] = (float)rp[j];
    }
    for (int i2 = t; i2 < DH * NC; i2 += 512) {
        sW[i2]           = W2l[i2];
        sW[DH * NC + i2] = W2r[i2];
    }
    if (t < NC) sW[2 * DH * NC + t] = b2[t];
    __syncthreads();

    // ---- tail: 2 rounds x (64 nodes x 8 lanes); 5 strided classes/lane ----
    int l8  = t & 7;
    int nb0 = t >> 3;                        // 0..63
    #pragma unroll
    for (int r = 0; r < 2; ++r) {
        int nl2 = nb0 + (r << 6);            // 0..127
        int nd  = (b << 7) + nl2;
        if (nd >= NN) continue;
        float av[DH], hv[DH];
        #pragma unroll
        for (int k = 0; k < DH; ++k) { av[k] = sA[nl2*17 + k]; hv[k] = sH[nl2*17 + k]; }
        float o[5];
        #pragma unroll
        for (int j = 0; j < 5; ++j) {
            int c = l8 + 8 * j;
            float acc = sW[2 * DH * NC + c];
            #pragma unroll
            for (int k = 0; k < DH; ++k) {
                acc = fmaf(av[k], sW[k * NC + c],           acc);
                acc = fmaf(hv[k], sW[DH * NC + k * NC + c], acc);
            }
            o[j] = acc;
        }
        float mx = o[0];
        #pragma unroll
        for (int j = 1; j < 5; ++j) mx = fmaxf(mx, o[j]);
        #pragma unroll
        for (int m = 1; m <= 4; m <<= 1) mx = fmaxf(mx, __shfl_xor(mx, m));
        float s = 0.f;
        #pragma unroll
        for (int j = 0; j < 5; ++j) s += __expf(o[j] - mx);
        #pragma unroll
        for (int m = 1; m <= 4; m <<= 1) s += __shfl_xor(s, m);
        float lg = mx + __logf(s);
        float* op = out + (long)nd * NC;
        #pragma unroll
        for (int j = 0; j < 5; ++j) op[l8 + 8 * j] = o[j] - lg;   // coalesced
    }
}

// ---------------- launch ----------------

extern "C" void kernel_launch(void* const* d_in, const int* in_sizes, int n_in,
                              void* d_out, int out_size, void* d_ws, size_t ws_size,
                              hipStream_t stream) {
    const float* x   = (const float*)d_in[0];
    const int*   ei  = (const int*)d_in[1];   // [2, E] int32
    const float* W1l = (const float*)d_in[2];
    const float* b1  = (const float*)d_in[3];
    const float* W1r = (const float*)d_in[4];
    const float* W2l = (const float*)d_in[5];
    const float* b2  = (const float*)d_in[6];
    const float* W2r = (const float*)d_in[7];
    float* out = (float*)d_out;

    const int E = in_sizes[1] / 2;
    const int* src = ei;
    const int* dst = ei + E;

    // ws (4B units): bcur[NB*16 pad 12544] | part[NB*BC] | p1r[16N f32] |
    //                p1h[16N f16] | h[16N f16]               (~21.7 MB)
    int* bcur = (int*)d_ws;
    int* part = bcur + 12544;
    float* p1r = (float*)(part + (long)NB * BC);
    f16*   p1h = (f16*)(p1r + (long)NN * DH);
    f16*   hh  = p1h + (long)NN * DH;

    hipMemsetAsync(bcur, 0, NB * BSTR * sizeof(int), stream);

    if ((E & 3) == 0)
        k_part<true ><<<(E + 8191) / 8192, 1024, 0, stream>>>(src, dst, E, bcur, part);
    else
        k_part<false><<<(E + 8191) / 8192, 1024, 0, stream>>>(src, dst, E, bcur, part);

    k_proj<<<(NN + 63) / 64, 256, 0, stream>>>(x, W1l, W1r, p1h, p1r);

    k_ba1<<<NB, 512, 0, stream>>>(bcur, part, (const uint4*)p1h,
                                  (const float4*)p1r, b1, (uint4*)hh);
    k_ba2<<<NB, 512, 0, stream>>>(bcur, part, (const uint4*)hh,
                                  W2l, b2, W2r, out);
}